// Round 5
// baseline (123.113 us; speedup 1.0000x reference)
//
#include <hip/hip_runtime.h>
#include <math.h>

#define HIDDEN 128
#define MAXBUK 512
#define E1_TPB 256
#define E1_EPT 4
#define E1_EPB (E1_TPB * E1_EPT)   // 1024 edges per block
#define E1_PPB (E1_EPB * 2)        // 2048 pairs per block

// W1P layout: [64][4][36] floats (32 used + 4 pad per chunk; 16B-aligned chunks,
// slices land on distinct banks for conflict-free 4-lane ds_read_b128)
#define W1P_K_STRIDE 144
#define W1P_S_STRIDE 36
#define W1P_FLOATS   (64 * W1P_K_STRIDE)

// ---------------------------------------------------------------------------
// Pack + prep fused:
//   all blocks: packed[n] = (h0,h1,<c0>,<c1>); netT[n] = (rain0,rain1)
//   blocks 0..15: build W1P (transposed+padded W1)    block 0: zero counters
// ---------------------------------------------------------------------------
__global__ __launch_bounds__(256) void pack_kernel(
    const float* __restrict__ h, const float* __restrict__ rain,
    const float* __restrict__ W1,
    float* __restrict__ packed, float* __restrict__ netT,
    float* __restrict__ W1P, unsigned* __restrict__ counters, int N)
{
    const int tid = threadIdx.x;
    const int b = blockIdx.x;
    if (b < 16) {
        // rows k in [4b, 4b+4): 512 elements
        for (int i = tid; i < 512; i += 256) {
            const int k = 4 * b + (i >> 7);
            const int hh = i & 127;
            const int s = hh >> 5, ii = hh & 31;
            W1P[k * W1P_K_STRIDE + s * W1P_S_STRIDE + ii] = W1[hh * 64 + k];
        }
        if (b == 0)
            for (int i = tid; i < MAXBUK; i += 256) counters[i] = 0u;
    }
    const int n = b * blockDim.x + tid;
    if (n >= N) return;
    *reinterpret_cast<float2*>(&packed[4 * n]) = make_float2(h[n], h[N + n]);
    *reinterpret_cast<float2*>(&netT[2 * n])   = make_float2(rain[n], rain[N + n]);
}

// ---------------------------------------------------------------------------
// Node kernel, 4-way sliced: 512 threads = 128 rows x 4 slices.
// slice owns 32 of 128 h-elems; k-partials combined via shfl_xor(1),(2)
// within the 4-lane group. W1 tile in LDS (padded layout, conflict-free).
//   coef  = sigmoid( gelu(z@W1+b1) @ W2 + b2 ) -> packed[n].{z|w}
//   areas = softplus( z@Wa + ba )              -> areas[r]
// ---------------------------------------------------------------------------
__global__ __launch_bounds__(512) void node_kernel(
    const float* __restrict__ z,     // [R][128]
    const float* __restrict__ W1P,   // [64][4][36]
    const float* __restrict__ b1, const float* __restrict__ W2,
    const float* __restrict__ b2, const float* __restrict__ Wa,
    const float* __restrict__ ba,
    float* __restrict__ packed, float* __restrict__ areas,
    int N, int R)
{
    __shared__ float w1s[W1P_FLOATS];   // 36864 B
    __shared__ float b1s[64], w2s[64], was[128];

    const int tid = threadIdx.x;
    for (int i = tid; i < W1P_FLOATS; i += 512) w1s[i] = W1P[i];
    if (tid < 64)       b1s[tid] = b1[tid];
    else if (tid < 128) w2s[tid - 64] = W2[tid - 64];
    else if (tid < 256) was[tid - 128] = Wa[tid - 128];
    __syncthreads();

    const int slice = tid & 3;
    const int r = blockIdx.x * 128 + (tid >> 2);
    const bool valid = (r < R);

    // this slice's 32 z-elements -> 32 VGPRs
    float zr[32];
    if (valid) {
        const float4* zp = reinterpret_cast<const float4*>(
            z + (size_t)r * HIDDEN + slice * 32);
#pragma unroll
        for (int i = 0; i < 8; ++i) {
            const float4 v = zp[i];
            zr[4 * i + 0] = v.x; zr[4 * i + 1] = v.y;
            zr[4 * i + 2] = v.z; zr[4 * i + 3] = v.w;
        }
    } else {
#pragma unroll
        for (int i = 0; i < 32; ++i) zr[i] = 0.f;
    }

    float cf = 0.f;
#pragma unroll 2
    for (int k = 0; k < 64; ++k) {
        const float* __restrict__ wk =
            &w1s[k * W1P_K_STRIDE + slice * W1P_S_STRIDE];
        float a0 = 0.f, a1 = 0.f;
#pragma unroll
        for (int i = 0; i < 8; ++i) {
            const float4 w = *reinterpret_cast<const float4*>(&wk[4 * i]);
            a0 = fmaf(zr[4 * i + 0], w.x, a0);
            a1 = fmaf(zr[4 * i + 1], w.y, a1);
            a0 = fmaf(zr[4 * i + 2], w.z, a0);
            a1 = fmaf(zr[4 * i + 3], w.w, a1);
        }
        float t = a0 + a1;
        t += __shfl_xor(t, 1, 64);      // combine 4 slices (same row group)
        t += __shfl_xor(t, 2, 64);
        const float x = t + b1s[k];
        const float g = 0.5f * x * (1.0f + erff(x * 0.70710678118654752f));
        cf = fmaf(g, w2s[k], cf);       // redundant across slices (identical)
    }

    float ad = 0.f;
#pragma unroll
    for (int i = 0; i < 32; ++i)
        ad = fmaf(zr[i], was[slice * 32 + i], ad);
    ad += __shfl_xor(ad, 1, 64);
    ad += __shfl_xor(ad, 2, 64);

    if (valid && slice == 0) {
        const float c    = 1.0f / (1.0f + expf(-(cf + b2[0])));
        const float adv  = ad + ba[0];
        const float area = fmaxf(adv, 0.f) + log1pf(expf(-fabsf(adv)));
        const int bb = (r >= N) ? 1 : 0;
        const int n = r - bb * N;
        packed[4 * n + 2 + bb] = c;
        areas[r] = area;
    }
}

// ---------------------------------------------------------------------------
// E1: per-edge flows + in-block counting-sort of (node, +/-f0,f1) pairs into
// per-bucket global segments (bucket = node>>8). ~196 int atomics per block.
// ---------------------------------------------------------------------------
__global__ __launch_bounds__(E1_TPB) void edge_bin_kernel(
    const int* __restrict__ eidx,      // [2][E]
    const float* __restrict__ packed,  // [N][4] = h0,h1,c0,c1
    float* __restrict__ flows,         // [2][E]
    unsigned* __restrict__ keysG,      // [nbuk][cap]
    float2* __restrict__ valsG,        // [nbuk][cap]
    unsigned* __restrict__ counters,   // [nbuk]
    int E, int nbuk, int cap)
{
    __shared__ unsigned hist[MAXBUK];
    __shared__ unsigned base[MAXBUK];
    __shared__ unsigned gbase[MAXBUK];
    __shared__ unsigned scan[E1_TPB];
    __shared__ unsigned skey[E1_PPB];
    __shared__ float2   sval[E1_PPB];

    const int tid = threadIdx.x;
    const int e0  = blockIdx.x * E1_EPB;

    for (int i = tid; i < nbuk; i += E1_TPB) hist[i] = 0;
    __syncthreads();

    unsigned mykey[2 * E1_EPT];
    unsigned myoff[2 * E1_EPT];
    float2   myval[2 * E1_EPT];

#pragma unroll
    for (int j = 0; j < E1_EPT; ++j) {
        const int e = e0 + j * E1_TPB + tid;
        unsigned kd = 0xFFFFFFFFu, ks = 0xFFFFFFFFu;
        float2 vd = make_float2(0.f, 0.f), vs = vd;
        if (e < E) {
            const int s = eidx[e];
            const int d = eidx[E + e];
            const float4 ps = *reinterpret_cast<const float4*>(&packed[4 * s]);
            const float4 pd = *reinterpret_cast<const float4*>(&packed[4 * d]);

            float dh = ps.x - pd.x;
            float sg = (dh > 0.f) ? 1.f : ((dh < 0.f) ? -1.f : 0.f);
            float f0 = ps.z * sg * sqrtf(fabsf(dh) + 1e-6f);
            f0 = fminf(fmaxf(f0, -10.0f), 10.0f);

            dh = ps.y - pd.y;
            sg = (dh > 0.f) ? 1.f : ((dh < 0.f) ? -1.f : 0.f);
            float f1 = ps.w * sg * sqrtf(fabsf(dh) + 1e-6f);
            f1 = fminf(fmaxf(f1, -10.0f), 10.0f);

            flows[e] = f0;
            flows[(size_t)E + e] = f1;

            kd = (unsigned)d; vd = make_float2(f0, f1);
            ks = (unsigned)s; vs = make_float2(-f0, -f1);
        }
        mykey[2 * j]     = kd; myval[2 * j]     = vd;
        mykey[2 * j + 1] = ks; myval[2 * j + 1] = vs;
        if (kd != 0xFFFFFFFFu) {
            myoff[2 * j]     = atomicAdd(&hist[kd >> 8], 1u);
            myoff[2 * j + 1] = atomicAdd(&hist[ks >> 8], 1u);
        }
    }
    __syncthreads();

    // Hillis-Steele inclusive scan of hist (nbuk <= 256)
    const unsigned hv = (tid < nbuk) ? hist[tid] : 0u;
    scan[tid] = hv;
    __syncthreads();
    for (int off = 1; off < E1_TPB; off <<= 1) {
        unsigned t = (tid >= off) ? scan[tid - off] : 0u;
        __syncthreads();
        scan[tid] += t;
        __syncthreads();
    }
    if (tid < nbuk) {
        base[tid] = scan[tid] - hv;
        if (hv > 0) gbase[tid] = atomicAdd(&counters[tid], hv);
    }
    __syncthreads();

#pragma unroll
    for (int j = 0; j < 2 * E1_EPT; ++j) {
        const unsigned k = mykey[j];
        if (k != 0xFFFFFFFFu) {
            const unsigned idx = base[k >> 8] + myoff[j];
            skey[idx] = k;
            sval[idx] = myval[j];
        }
    }
    __syncthreads();

    const int tot = 2 * min(E1_EPB, E - e0);
    for (int i = tid; i < tot; i += E1_TPB) {
        const unsigned k = skey[i];
        const unsigned bb = k >> 8;
        const unsigned pos = gbase[bb] + ((unsigned)i - base[bb]);
        if (pos < (unsigned)cap) {
            keysG[(size_t)bb * cap + pos] = k;
            valsG[(size_t)bb * cap + pos] = sval[i];
        }
    }
}

// ---------------------------------------------------------------------------
// E2: one block (512 thr) per bucket; dual LDS accumulator copies halve
// atomic serialization. Fused h-update. No global f32 atomics.
// ---------------------------------------------------------------------------
__global__ __launch_bounds__(512) void bucket_reduce_kernel(
    const unsigned* __restrict__ keysG, const float2* __restrict__ valsG,
    const unsigned* __restrict__ counters,
    const float* __restrict__ h, const float* __restrict__ rain,
    const float* __restrict__ areas,
    float* __restrict__ hnew, int N, int cap)
{
    __shared__ float accx[2][256], accy[2][256];
    const int tid = threadIdx.x;
    const int b = blockIdx.x;
    const int half = tid >> 8;
    if (tid < 256) { accx[0][tid] = 0.f; accy[0][tid] = 0.f; }
    else           { accx[1][tid - 256] = 0.f; accy[1][tid - 256] = 0.f; }
    __syncthreads();

    const int cnt = min((int)counters[b], cap);
    const unsigned* __restrict__ sk = keysG + (size_t)b * cap;
    const float2*  __restrict__  sv = valsG + (size_t)b * cap;
    for (int i = tid; i < cnt; i += 512) {
        const unsigned k = sk[i];
        const float2 v2 = sv[i];
        const int loc = (int)(k & 255u);
        atomicAdd(&accx[half][loc], v2.x);
        atomicAdd(&accy[half][loc], v2.y);
    }
    __syncthreads();

    if (tid < 256) {
        const int n = (b << 8) + tid;
        if (n < N) {
            const float net0 = rain[n]     + accx[0][tid] + accx[1][tid];
            const float net1 = rain[N + n] + accy[0][tid] + accy[1][tid];
            float dh0 = 300.0f * net0 / (areas[n] + 1e-6f);
            dh0 = fminf(fmaxf(dh0, -1.0f), 1.0f);
            hnew[n] = h[n] + dh0;
            float dh1 = 300.0f * net1 / (areas[N + n] + 1e-6f);
            dh1 = fminf(fmaxf(dh1, -1.0f), 1.0f);
            hnew[N + n] = h[N + n] + dh1;
        }
    }
}

// ---------------------------------------------------------------------------
// Fallback path (ws too small): atomic edge + update kernels.
// ---------------------------------------------------------------------------
__global__ __launch_bounds__(256) void edge_kernel(
    const int* __restrict__ eidx, const float* __restrict__ packed,
    float* __restrict__ flows, float* __restrict__ netT, int E)
{
    const int e = blockIdx.x * blockDim.x + threadIdx.x;
    if (e >= E) return;
    const int s = eidx[e];
    const int d = eidx[E + e];
    const float4 ps = *reinterpret_cast<const float4*>(&packed[4 * s]);
    const float4 pd = *reinterpret_cast<const float4*>(&packed[4 * d]);
    {
        const float dh = ps.x - pd.x;
        const float sg = (dh > 0.f) ? 1.f : ((dh < 0.f) ? -1.f : 0.f);
        float f = ps.z * sg * sqrtf(fabsf(dh) + 1e-6f);
        f = fminf(fmaxf(f, -10.0f), 10.0f);
        flows[e] = f;
        unsafeAtomicAdd(&netT[2 * d + 0],  f);
        unsafeAtomicAdd(&netT[2 * s + 0], -f);
    }
    {
        const float dh = ps.y - pd.y;
        const float sg = (dh > 0.f) ? 1.f : ((dh < 0.f) ? -1.f : 0.f);
        float f = ps.w * sg * sqrtf(fabsf(dh) + 1e-6f);
        f = fminf(fmaxf(f, -10.0f), 10.0f);
        flows[(size_t)E + e] = f;
        unsafeAtomicAdd(&netT[2 * d + 1],  f);
        unsafeAtomicAdd(&netT[2 * s + 1], -f);
    }
}

__global__ __launch_bounds__(256) void update_kernel(
    const float* __restrict__ h, const float* __restrict__ netT,
    const float* __restrict__ areas, float* __restrict__ hnew, int N)
{
    const int n = blockIdx.x * blockDim.x + threadIdx.x;
    if (n >= N) return;
    const float2 nv = *reinterpret_cast<const float2*>(&netT[2 * n]);
    float dh0 = 300.0f * nv.x / (areas[n] + 1e-6f);
    dh0 = fminf(fmaxf(dh0, -1.0f), 1.0f);
    hnew[n] = h[n] + dh0;
    float dh1 = 300.0f * nv.y / (areas[N + n] + 1e-6f);
    dh1 = fminf(fmaxf(dh1, -1.0f), 1.0f);
    hnew[N + n] = h[N + n] + dh1;
}

extern "C" void kernel_launch(void* const* d_in, const int* in_sizes, int n_in,
                              void* d_out, int out_size, void* d_ws, size_t ws_size,
                              hipStream_t stream)
{
    const float* h    = (const float*)d_in[0];
    const float* z    = (const float*)d_in[1];
    const int*   eidx = (const int*)  d_in[2];
    const float* rain = (const float*)d_in[4];
    const float* W1   = (const float*)d_in[5];
    const float* b1   = (const float*)d_in[6];
    const float* W2   = (const float*)d_in[7];
    const float* b2   = (const float*)d_in[8];
    const float* Wa   = (const float*)d_in[9];
    const float* ba   = (const float*)d_in[10];

    const int R = in_sizes[0];      // B*N
    const int E = in_sizes[3];
    const int N = R / 2;

    float* out_h     = (float*)d_out;
    float* out_flows = out_h + R;

    char* wsB = (char*)d_ws;
    size_t off = 0;
    auto take = [&](size_t bytes) -> char* {
        char* p = wsB + off;
        off = (off + bytes + 255) & ~(size_t)255;
        return p;
    };
    float*    packed   = (float*)   take((size_t)4 * N * 4);
    float*    areas    = (float*)   take((size_t)R * 4);
    float*    netT     = (float*)   take((size_t)2 * N * 4);
    float*    W1P      = (float*)   take(W1P_FLOATS * 4);
    unsigned* counters = (unsigned*)take(MAXBUK * 4);

    const int nbuk = (N + 255) >> 8;
    int cap = (int)(((size_t)2 * E / (nbuk > 0 ? nbuk : 1)) * 5 / 4 + 512);
    cap = (cap + 255) & ~255;
    unsigned* keysG = (unsigned*)take((size_t)nbuk * cap * 4);
    float2*   valsG = (float2*)  take((size_t)nbuk * cap * 8);
    const bool binned = (off <= ws_size) && (nbuk <= 256);

    const int packBlocks = max((N + 255) / 256, 16);
    pack_kernel<<<packBlocks, 256, 0, stream>>>(h, rain, W1, packed, netT,
                                                W1P, counters, N);
    node_kernel<<<(R + 127) / 128, 512, 0, stream>>>(z, W1P, b1, W2, b2, Wa, ba,
                                                     packed, areas, N, R);
    if (binned) {
        edge_bin_kernel<<<(E + E1_EPB - 1) / E1_EPB, E1_TPB, 0, stream>>>(
            eidx, packed, out_flows, keysG, valsG, counters, E, nbuk, cap);
        bucket_reduce_kernel<<<nbuk, 512, 0, stream>>>(
            keysG, valsG, counters, h, rain, areas, out_h, N, cap);
    } else {
        edge_kernel<<<(E + 255) / 256, 256, 0, stream>>>(eidx, packed,
                                                         out_flows, netT, E);
        update_kernel<<<(N + 255) / 256, 256, 0, stream>>>(h, netT, areas,
                                                           out_h, N);
    }
}